// Round 5
// baseline (190.046 us; speedup 1.0000x reference)
//
#include <hip/hip_runtime.h>
#include <hip/hip_cooperative_groups.h>
#include <math.h>

namespace cg = cooperative_groups;

#define NB 64
#define NN 512
#define ND 128

typedef __attribute__((ext_vector_type(8))) short short8;
typedef __attribute__((ext_vector_type(4))) float f32x4;

// workspace layout (floats)
#define KVB_OFF   0                         // kv bf16: NB*NN*ND ushorts
#define QK_OFF    (NB*NN*ND/2)
#define QSUMP_OFF (QK_OFF + NB*NN)          // qsum partials: NB*4*ND floats

__device__ inline unsigned short f2bf(float x) {
    unsigned int u = __float_as_uint(x);
    return (unsigned short)((u + 0x7FFFu + ((u >> 16) & 1u)) >> 16);
}
__device__ inline float bf2f(unsigned short u) {
    return __uint_as_float(((unsigned int)u) << 16);
}

// One cooperative kernel: proj (MFMA) -> grid.sync -> fused attn.
// Grid 256 x 256: block = b*4 + chunk (proj) = b*4 + cg (fused).
__global__ __launch_bounds__(256, 1) void ga_all(
    const float* __restrict__ aq, const float* __restrict__ mask,
    const float* __restrict__ Wq, const float* __restrict__ bq,
    const float* __restrict__ Wk, const float* __restrict__ bk,
    unsigned short* __restrict__ kvb, float* __restrict__ qk,
    float* __restrict__ qsum_part,
    float* __restrict__ out_attn, float* __restrict__ out_ctx)
{
    cg::grid_group grid = cg::this_grid();

    __shared__ __align__(16) unsigned short a_lds[128][136];  // pitch 136
    __shared__ float mask_lds[128];
    __shared__ float qk_part[4][128];
    // phase-2 shared
    __shared__ float qs[128];
    __shared__ float mask_s[512];
    __shared__ float agg_s[512];
    __shared__ float red[8];
    __shared__ float bc2[2];
    __shared__ float zred[4];
    __shared__ float zbc;
    __shared__ float ctx_part[8][32];

    const int b    = blockIdx.x >> 2;
    const int m0   = (blockIdx.x & 3) << 7;
    const int t    = threadIdx.x;
    const int w    = t >> 6, lane = t & 63;
    const int quad = lane >> 4, l16 = lane & 15;

    // ================= Phase 1: projection =================
    // stage aq tile fp32 -> bf16 LDS (coalesced float4 reads)
    {
        const float4* src = (const float4*)(aq + ((size_t)b*NN + m0)*ND);
        #pragma unroll
        for (int i = 0; i < 16; i++) {
            const int idx = t + 256*i;
            const int row = idx >> 5, c4 = idx & 31;
            const float4 v = src[idx];
            ushort4 o;
            o.x = f2bf(v.x); o.y = f2bf(v.y); o.z = f2bf(v.z); o.w = f2bf(v.w);
            *(ushort4*)&a_lds[row][c4*4] = o;
        }
        if (t < 128) mask_lds[t] = mask[b*NN + m0 + t];
    }

    // B fragments gathered directly from global fp32 W (L2-hot, 128 KB total).
    // nt 0,1 = q cols [w*32, w*32+32); nt 2,3 = k cols same range.
    short8 bfr[4][4];
    #pragma unroll
    for (int nt = 0; nt < 4; nt++) {
        const float* Wsrc = (nt < 2) ? Wq : Wk;
        const int col = w*32 + (nt & 1)*16 + l16;
        #pragma unroll
        for (int kc = 0; kc < 4; kc++) {
            unsigned short tmp[8];
            #pragma unroll
            for (int j = 0; j < 8; j++)
                tmp[j] = f2bf(Wsrc[(kc*32 + quad*8 + j)*ND + col]);
            bfr[nt][kc] = *(const short8*)tmp;
        }
    }

    __syncthreads();

    f32x4 acc[8][4];
    #pragma unroll
    for (int m = 0; m < 8; m++)
        #pragma unroll
        for (int nt = 0; nt < 4; nt++)
            acc[m][nt] = (f32x4){0.f, 0.f, 0.f, 0.f};

    #pragma unroll
    for (int m = 0; m < 8; m++) {
        short8 afr[4];
        #pragma unroll
        for (int kc = 0; kc < 4; kc++)
            afr[kc] = *(const short8*)&a_lds[m*16 + l16][kc*32 + quad*8];
        #pragma unroll
        for (int nt = 0; nt < 4; nt++)
            #pragma unroll
            for (int kc = 0; kc < 4; kc++)
                acc[m][nt] = __builtin_amdgcn_mfma_f32_16x16x32_bf16(
                    afr[kc], bfr[nt][kc], acc[m][nt], 0, 0, 0);
    }

    // bias
    float bv[4];
    #pragma unroll
    for (int nt = 0; nt < 2; nt++) bv[nt] = bq[w*32 + nt*16 + l16];
    #pragma unroll
    for (int nt = 2; nt < 4; nt++) bv[nt] = bk[w*32 + (nt-2)*16 + l16];
    #pragma unroll
    for (int m = 0; m < 8; m++)
        #pragma unroll
        for (int nt = 0; nt < 4; nt++)
            #pragma unroll
            for (int r = 0; r < 4; r++)
                acc[m][nt][r] += bv[nt];

    // store k rows as bf16 (C layout: row = m*16 + quad*4 + r, col = base + l16)
    #pragma unroll
    for (int m = 0; m < 8; m++)
        #pragma unroll
        for (int r = 0; r < 4; r++) {
            const size_t row = (size_t)b*NN + m0 + m*16 + quad*4 + r;
            kvb[row*ND + w*32 + l16]      = f2bf(acc[m][2][r]);
            kvb[row*ND + w*32 + 16 + l16] = f2bf(acc[m][3][r]);
        }

    // qk partial: q.k over this wave's 32 d-cols (full fp32 precision)
    #pragma unroll
    for (int m = 0; m < 8; m++) {
        float p[4];
        #pragma unroll
        for (int r = 0; r < 4; r++)
            p[r] = acc[m][0][r]*acc[m][2][r] + acc[m][1][r]*acc[m][3][r];
        #pragma unroll
        for (int off = 1; off <= 8; off <<= 1)
            #pragma unroll
            for (int r = 0; r < 4; r++)
                p[r] += __shfl_xor(p[r], off);
        if (l16 == 0)
            #pragma unroll
            for (int r = 0; r < 4; r++)
                qk_part[w][m*16 + quad*4 + r] = p[r];
    }

    // qsum partial: disjoint slots, plain stores
    {
        float s0 = 0.f, s1 = 0.f;
        #pragma unroll
        for (int m = 0; m < 8; m++)
            #pragma unroll
            for (int r = 0; r < 4; r++) {
                const float mk = mask_lds[m*16 + quad*4 + r];
                s0 += mk * acc[m][0][r];
                s1 += mk * acc[m][1][r];
            }
        s0 += __shfl_xor(s0, 16); s0 += __shfl_xor(s0, 32);
        s1 += __shfl_xor(s1, 16); s1 += __shfl_xor(s1, 32);
        if (quad == 0) {
            const int slot = blockIdx.x * ND;
            qsum_part[slot + w*32 + l16]      = s0;
            qsum_part[slot + w*32 + 16 + l16] = s1;
        }
    }

    __syncthreads();
    if (t < 128)
        qk[(size_t)b*NN + m0 + t] =
            qk_part[0][t] + qk_part[1][t] + qk_part[2][t] + qk_part[3][t];

    __threadfence();
    grid.sync();

    // ================= Phase 2: fused attention =================
    const int cg_ = blockIdx.x & 3;
    const size_t rowbase = (size_t)b * NN;

    if (t < 128)
        qs[t] = qsum_part[(b*4 + 0)*ND + t] + qsum_part[(b*4 + 1)*ND + t]
              + qsum_part[(b*4 + 2)*ND + t] + qsum_part[(b*4 + 3)*ND + t];
    mask_s[t]       = mask[rowbase + t];
    mask_s[t + 256] = mask[rowbase + t + 256];
    __syncthreads();

    const int h = lane & 31, half = lane >> 5;
    float qsf[4];
    #pragma unroll
    for (int j = 0; j < 4; j++) qsf[j] = qs[h*4 + j];

    // Phase A: agg[n] for all 512 n; wave w owns rows w*128..w*128+127
    for (int i0 = 0; i0 < 128; i0 += 4) {
        const int na  = w*128 + i0 + half;     // rows +0,+1
        const int nb2 = na + 2;                // rows +2,+3
        const ushort4 ka = *(const ushort4*)(kvb + (rowbase + na)*ND + h*4);
        const ushort4 kb = *(const ushort4*)(kvb + (rowbase + nb2)*ND + h*4);
        float p0 = bf2f(ka.x)*qsf[0] + bf2f(ka.y)*qsf[1]
                 + bf2f(ka.z)*qsf[2] + bf2f(ka.w)*qsf[3];
        float p1 = bf2f(kb.x)*qsf[0] + bf2f(kb.y)*qsf[1]
                 + bf2f(kb.z)*qsf[2] + bf2f(kb.w)*qsf[3];
        #pragma unroll
        for (int off = 1; off <= 16; off <<= 1) {
            p0 += __shfl_xor(p0, off);
            p1 += __shfl_xor(p1, off);
        }
        if (h == 0) {
            agg_s[na]  = mask_s[na]  * (p0 - qk[rowbase + na]);
            agg_s[nb2] = mask_s[nb2] * (p1 - qk[rowbase + nb2]);
        }
    }
    __syncthreads();

    // Phase B: norm2 + masked max (thread t owns rows t and t+256)
    const float v0 = agg_s[t], v1 = agg_s[t + 256];
    const bool um0 = mask_s[t] != 0.f, um1 = mask_s[t + 256] != 0.f;
    float sq = v0*v0 + v1*v1;
    float mx = fmaxf(um0 ? v0 : -3.0e38f, um1 ? v1 : -3.0e38f);
    #pragma unroll
    for (int off = 1; off <= 32; off <<= 1) {
        sq += __shfl_xor(sq, off);
        mx = fmaxf(mx, __shfl_xor(mx, off));
    }
    if (lane == 0) { red[w] = sq; red[4 + w] = mx; }
    __syncthreads();
    if (t == 0) {
        float s = 0.f, m = -3.0e38f;
        #pragma unroll
        for (int i = 0; i < 4; i++) { s += red[i]; m = fmaxf(m, red[4 + i]); }
        bc2[0] = sqrtf(s);
        bc2[1] = m;
    }
    __syncthreads();
    const float nrm = bc2[0];
    const float M   = bc2[1];

    // Phase C: masked exp + Z
    const float e0 = um0 ? expf((v0 - M) / nrm) : 0.f;
    const float e1 = um1 ? expf((v1 - M) / nrm) : 0.f;
    float z = e0 + e1;
    #pragma unroll
    for (int off = 1; off <= 32; off <<= 1) z += __shfl_xor(z, off);
    if (lane == 0) zred[w] = z;
    agg_s[t] = e0;            // own slots only
    agg_s[t + 256] = e1;
    __syncthreads();
    if (t == 0) zbc = zred[0] + zred[1] + zred[2] + zred[3];
    __syncthreads();
    const float Z = zbc;
    if (cg_ == 0) {
        out_attn[rowbase + t]       = e0 / Z;
        out_attn[rowbase + t + 256] = e1 / Z;
    }

    // Phase D: context slice, cols [cg*32, cg*32+32)
    const int col = cg_*32 + (t & 31);
    const int rg  = t >> 5;              // 8 row groups
    float a = 0.f;
    for (int n = rg; n < NN; n += 8)
        a += agg_s[n] * bf2f(kvb[(rowbase + n)*ND + col]);
    ctx_part[rg][t & 31] = a;
    __syncthreads();
    if (t < 32) {
        float s = 0.f;
        #pragma unroll
        for (int i = 0; i < 8; i++) s += ctx_part[i][t];
        out_ctx[(size_t)b*ND + cg_*32 + t] = s / Z;
    }
}

extern "C" void kernel_launch(void* const* d_in, const int* in_sizes, int n_in,
                              void* d_out, int out_size, void* d_ws, size_t ws_size,
                              hipStream_t stream)
{
    const float* aq   = (const float*)d_in[0];
    const float* mask = (const float*)d_in[1];
    const float* Wq   = (const float*)d_in[2];
    const float* bq   = (const float*)d_in[3];
    const float* Wk   = (const float*)d_in[4];
    const float* bk   = (const float*)d_in[5];

    float* ws = (float*)d_ws;
    unsigned short* kvb       = (unsigned short*)(ws + KVB_OFF);
    float*          qk        = ws + QK_OFF;
    float*          qsum_part = ws + QSUMP_OFF;

    float* out_attn = (float*)d_out;
    float* out_ctx  = (float*)d_out + NB*NN;

    void* args[] = { (void*)&aq, (void*)&mask, (void*)&Wq, (void*)&bq,
                     (void*)&Wk, (void*)&bk, (void*)&kvb, (void*)&qk,
                     (void*)&qsum_part, (void*)&out_attn, (void*)&out_ctx };
    hipLaunchCooperativeKernel((const void*)ga_all, dim3(256), dim3(256),
                               args, 0, stream);
}

// Round 6
// 96.885 us; speedup vs baseline: 1.9616x; 1.9616x over previous
//
#include <hip/hip_runtime.h>
#include <math.h>

#define NB 64
#define NN 512
#define ND 128

typedef __attribute__((ext_vector_type(8))) short short8;
typedef __attribute__((ext_vector_type(4))) float f32x4;

// workspace layout (floats)
#define KVB_OFF   0                         // kv bf16: NB*NN*ND ushorts
#define QK_OFF    (NB*NN*ND/2)
#define QSUMP_OFF (QK_OFF + NB*NN)          // qsum partials: NB*4*ND floats

__device__ inline unsigned short f2bf(float x) {
    unsigned int u = __float_as_uint(x);
    return (unsigned short)((u + 0x7FFFu + ((u >> 16) & 1u)) >> 16);
}
__device__ inline float bf2f(unsigned short u) {
    return __uint_as_float(((unsigned int)u) << 16);
}

// K1: bf16 MFMA projection, W transposed in-block (no conv_w kernel).
// Per block: 128 rows x (128 q-cols + 128 k-cols).
// Emits kvb (k proj, bf16), qk[b,n] = q.k (fp32), qsum_part[b*4+chunk][d].
__global__ __launch_bounds__(256, 1) void proj_mfma(
    const float* __restrict__ aq, const float* __restrict__ mask,
    const float* __restrict__ Wq, const float* __restrict__ bq,
    const float* __restrict__ Wk, const float* __restrict__ bk,
    unsigned short* __restrict__ kvb, float* __restrict__ qk,
    float* __restrict__ qsum_part)
{
    // one 34816-B buffer, reused: Wq stage -> Wk stage -> A tile
    __shared__ __align__(16) unsigned char sbuf[34816];
    unsigned short (*wst)[132] = (unsigned short (*)[132])sbuf;  // [128][132]
    unsigned short (*ast)[136] = (unsigned short (*)[136])sbuf;  // [128][136]
    __shared__ float mask_lds[128];
    __shared__ float qk_part[4][128];

    const int b    = blockIdx.x >> 2;
    const int m0   = (blockIdx.x & 3) << 7;
    const int t    = threadIdx.x;
    const int w    = t >> 6, lane = t & 63;
    const int quad = lane >> 4, l16 = lane & 15;

    short8 bfr[4][4];

    // ---- stage Wq (fp32, coalesced) -> bf16 LDS [k][col], extract q-frags ----
    #pragma unroll
    for (int s = 0; s < 2; s++) {               // s=0: Wq -> nt 0,1 ; s=1: Wk -> nt 2,3
        const float* Wsrc = s ? Wk : Wq;
        if (s) __syncthreads();                 // protect previous frag reads
        {
            const float4* src = (const float4*)Wsrc;
            #pragma unroll
            for (int i = 0; i < 16; i++) {
                const int idx = t + 256*i;      // 4096 float4 = 16384 floats
                const int row = idx >> 5, c4 = idx & 31;
                const float4 v = src[idx];
                ushort4 o;
                o.x = f2bf(v.x); o.y = f2bf(v.y); o.z = f2bf(v.z); o.w = f2bf(v.w);
                *(ushort4*)&wst[row][c4*4] = o;
            }
        }
        __syncthreads();
        #pragma unroll
        for (int nt = 0; nt < 2; nt++) {
            const int col = w*32 + nt*16 + l16;
            #pragma unroll
            for (int kc = 0; kc < 4; kc++) {
                short8 v;
                #pragma unroll
                for (int j = 0; j < 8; j++)
                    v[j] = (short)wst[kc*32 + quad*8 + j][col];
                bfr[s*2 + nt][kc] = v;
            }
        }
    }
    __syncthreads();

    // ---- stage aq tile fp32 -> bf16 LDS (coalesced float4 reads) ----
    {
        const float4* src = (const float4*)(aq + ((size_t)b*NN + m0)*ND);
        #pragma unroll
        for (int i = 0; i < 16; i++) {
            const int idx = t + 256*i;
            const int row = idx >> 5, c4 = idx & 31;
            const float4 v = src[idx];
            ushort4 o;
            o.x = f2bf(v.x); o.y = f2bf(v.y); o.z = f2bf(v.z); o.w = f2bf(v.w);
            *(ushort4*)&ast[row][c4*4] = o;
        }
        if (t < 128) mask_lds[t] = mask[b*NN + m0 + t];
    }
    __syncthreads();

    f32x4 acc[8][4];
    #pragma unroll
    for (int m = 0; m < 8; m++)
        #pragma unroll
        for (int nt = 0; nt < 4; nt++)
            acc[m][nt] = (f32x4){0.f, 0.f, 0.f, 0.f};

    #pragma unroll
    for (int m = 0; m < 8; m++) {
        short8 afr[4];
        #pragma unroll
        for (int kc = 0; kc < 4; kc++)
            afr[kc] = *(const short8*)&ast[m*16 + l16][kc*32 + quad*8];
        #pragma unroll
        for (int nt = 0; nt < 4; nt++)
            #pragma unroll
            for (int kc = 0; kc < 4; kc++)
                acc[m][nt] = __builtin_amdgcn_mfma_f32_16x16x32_bf16(
                    afr[kc], bfr[nt][kc], acc[m][nt], 0, 0, 0);
    }

    // bias
    float bv[4];
    #pragma unroll
    for (int nt = 0; nt < 2; nt++) bv[nt] = bq[w*32 + nt*16 + l16];
    #pragma unroll
    for (int nt = 2; nt < 4; nt++) bv[nt] = bk[w*32 + (nt-2)*16 + l16];
    #pragma unroll
    for (int m = 0; m < 8; m++)
        #pragma unroll
        for (int nt = 0; nt < 4; nt++)
            #pragma unroll
            for (int r = 0; r < 4; r++)
                acc[m][nt][r] += bv[nt];

    // store k rows as bf16 (C layout: row = m*16 + quad*4 + r, col = base + l16)
    #pragma unroll
    for (int m = 0; m < 8; m++)
        #pragma unroll
        for (int r = 0; r < 4; r++) {
            const size_t row = (size_t)b*NN + m0 + m*16 + quad*4 + r;
            kvb[row*ND + w*32 + l16]      = f2bf(acc[m][2][r]);
            kvb[row*ND + w*32 + 16 + l16] = f2bf(acc[m][3][r]);
        }

    // qk partial: q.k over this wave's 32 d-cols (full fp32 precision)
    #pragma unroll
    for (int m = 0; m < 8; m++) {
        float p[4];
        #pragma unroll
        for (int r = 0; r < 4; r++)
            p[r] = acc[m][0][r]*acc[m][2][r] + acc[m][1][r]*acc[m][3][r];
        #pragma unroll
        for (int off = 1; off <= 8; off <<= 1)
            #pragma unroll
            for (int r = 0; r < 4; r++)
                p[r] += __shfl_xor(p[r], off);
        if (l16 == 0)
            #pragma unroll
            for (int r = 0; r < 4; r++)
                qk_part[w][m*16 + quad*4 + r] = p[r];
    }

    // qsum partial: disjoint slots, plain stores (no atomics, no memset)
    {
        float s0 = 0.f, s1 = 0.f;
        #pragma unroll
        for (int m = 0; m < 8; m++)
            #pragma unroll
            for (int r = 0; r < 4; r++) {
                const float mk = mask_lds[m*16 + quad*4 + r];
                s0 += mk * acc[m][0][r];
                s1 += mk * acc[m][1][r];
            }
        s0 += __shfl_xor(s0, 16); s0 += __shfl_xor(s0, 32);
        s1 += __shfl_xor(s1, 16); s1 += __shfl_xor(s1, 32);
        if (quad == 0) {
            const int slot = blockIdx.x * ND;
            qsum_part[slot + w*32 + l16]      = s0;
            qsum_part[slot + w*32 + 16 + l16] = s1;
        }
    }

    __syncthreads();
    if (t < 128)
        qk[(size_t)b*NN + m0 + t] =
            qk_part[0][t] + qk_part[1][t] + qk_part[2][t] + qk_part[3][t];
}

// K2: fused agg + norm + softmax + context. Grid: b*4 + cg, 512 threads.
__global__ __launch_bounds__(512) void fused_attn(
    const float* __restrict__ mask, const unsigned short* __restrict__ kvb,
    const float* __restrict__ qk, const float* __restrict__ qsum_part,
    float* __restrict__ out_attn, float* __restrict__ out_ctx)
{
    __shared__ float qs[128];
    __shared__ float mask_s[512];
    __shared__ float agg_s[512];          // then reused to hold e
    __shared__ float red[16];
    __shared__ float bc2[2];
    __shared__ float zred[8];
    __shared__ float zbc;
    __shared__ float ctx_part[32][33];    // pad 33 -> conflict-free column read

    const int b  = blockIdx.x >> 2;
    const int cg = blockIdx.x & 3;
    const int t = threadIdx.x, w = t >> 6, lane = t & 63;
    const size_t rowbase = (size_t)b * NN;

    if (t < 128)
        qs[t] = qsum_part[(b*4 + 0)*ND + t] + qsum_part[(b*4 + 1)*ND + t]
              + qsum_part[(b*4 + 2)*ND + t] + qsum_part[(b*4 + 3)*ND + t];
    mask_s[t] = mask[rowbase + t];
    __syncthreads();

    // Phase A: agg[n]; 16 lanes per row (ushort8 = 8 d each), 4 rows/wave-pass
    const int h = lane & 15, quad = lane >> 4;
    float qsf[8];
    #pragma unroll
    for (int j = 0; j < 8; j++) qsf[j] = qs[h*8 + j];

    for (int i0 = 0; i0 < 64; i0 += 4) {
        const int n = w*64 + i0 + quad;
        const short8 kr = *(const short8*)(kvb + (rowbase + n)*ND + h*8);
        float p = 0.f;
        #pragma unroll
        for (int j = 0; j < 8; j++)
            p += bf2f((unsigned short)kr[j]) * qsf[j];
        #pragma unroll
        for (int off = 1; off <= 8; off <<= 1) p += __shfl_xor(p, off);
        if (h == 0)
            agg_s[n] = mask_s[n] * (p - qk[rowbase + n]);
    }
    __syncthreads();

    // Phase B: norm2 + masked max over 512 rows (thread t owns row t)
    const float v  = agg_s[t];
    const bool um  = mask_s[t] != 0.f;
    float sq = v * v;
    float mx = um ? v : -3.0e38f;
    #pragma unroll
    for (int off = 1; off <= 32; off <<= 1) {
        sq += __shfl_xor(sq, off);
        mx = fmaxf(mx, __shfl_xor(mx, off));
    }
    if (lane == 0) { red[w] = sq; red[8 + w] = mx; }
    __syncthreads();
    if (t == 0) {
        float s = 0.f, m = -3.0e38f;
        #pragma unroll
        for (int i = 0; i < 8; i++) { s += red[i]; m = fmaxf(m, red[8 + i]); }
        bc2[0] = sqrtf(s);
        bc2[1] = m;
    }
    __syncthreads();
    const float nrm = bc2[0];
    const float M   = bc2[1];

    // Phase C: masked exp + Z
    const float e = um ? expf((v - M) / nrm) : 0.f;
    float z = e;
    #pragma unroll
    for (int off = 1; off <= 32; off <<= 1) z += __shfl_xor(z, off);
    if (lane == 0) zred[w] = z;
    agg_s[t] = e;                 // own slot only
    __syncthreads();
    if (t == 0) {
        float s = 0.f;
        #pragma unroll
        for (int i = 0; i < 8; i++) s += zred[i];
        zbc = s;
    }
    __syncthreads();
    const float Z = zbc;
    if (cg == 0) out_attn[rowbase + t] = e / Z;

    // Phase D: context slice, cols [cg*32, cg*32+32); ushort2 loads
    const int c2  = (t & 15) * 2;        // 0,2,..,30 within slice
    const int col = cg*32 + c2;
    const int rg  = t >> 4;              // 32 row groups
    float a0 = 0.f, a1 = 0.f;
    for (int n = rg; n < NN; n += 32) {
        const ushort2 kk = *(const ushort2*)(kvb + (rowbase + n)*ND + col);
        const float ev = agg_s[n];
        a0 += ev * bf2f(kk.x);
        a1 += ev * bf2f(kk.y);
    }
    ctx_part[rg][c2]     = a0;
    ctx_part[rg][c2 + 1] = a1;
    __syncthreads();
    if (t < 32) {
        float s = 0.f;
        #pragma unroll
        for (int i = 0; i < 32; i++) s += ctx_part[i][t];
        out_ctx[(size_t)b*ND + cg*32 + t] = s / Z;
    }
}

extern "C" void kernel_launch(void* const* d_in, const int* in_sizes, int n_in,
                              void* d_out, int out_size, void* d_ws, size_t ws_size,
                              hipStream_t stream)
{
    const float* aq   = (const float*)d_in[0];
    const float* mask = (const float*)d_in[1];
    const float* Wq   = (const float*)d_in[2];
    const float* bq   = (const float*)d_in[3];
    const float* Wk   = (const float*)d_in[4];
    const float* bk   = (const float*)d_in[5];

    float* ws = (float*)d_ws;
    unsigned short* kvb       = (unsigned short*)(ws + KVB_OFF);
    float*          qk        = ws + QK_OFF;
    float*          qsum_part = ws + QSUMP_OFF;

    float* out_attn = (float*)d_out;
    float* out_ctx  = (float*)d_out + NB*NN;

    proj_mfma<<<dim3(256), dim3(256), 0, stream>>>(aq, mask, Wq, bq, Wk, bk,
                                                   kvb, qk, qsum_part);
    fused_attn<<<dim3(256), dim3(512), 0, stream>>>(mask, kvb, qk, qsum_part,
                                                    out_attn, out_ctx);
}